// Round 1
// 962.986 us; speedup vs baseline: 1.4268x; 1.4268x over previous
//
#include <hip/hip_runtime.h>
#include <stdint.h>
#include <math.h>

// Problem constants (from reference)
#define T_STEPS 128
#define NB      128
#define HID     64
#define CONVOUT 4096
#define NSUB    5
#define SUBSZ   14      // A+B+C = 5+3+6
#define NG      90      // A*B*C
#define STATE   99
#define DIN     4111    // CONVOUT + 3*NSUB
#define WFCOLS  4125    // CONVOUT + 2*SUBSZ + 1
#define WBCOLS  4110    // CONVOUT + SUBSZ
#define NROWS   (T_STEPS * NB)   // 16384

// ---------------- Threefry-2x32 (JAX-compatible) ----------------
__device__ __forceinline__ void tf2x32(unsigned k0, unsigned k1,
                                       unsigned x0, unsigned x1,
                                       unsigned &o0, unsigned &o1) {
  unsigned K0 = k0, K1 = k1, K2 = k0 ^ k1 ^ 0x1BD11BDAu;
  x0 += K0; x1 += K1;
  const int R0[4] = {13, 15, 26, 6};
  const int R1[4] = {17, 29, 16, 24};
  #pragma unroll
  for (int j = 0; j < 4; ++j) { x0 += x1; x1 = (x1 << R0[j]) | (x1 >> (32 - R0[j])); x1 ^= x0; }
  x0 += K1; x1 += K2 + 1u;
  #pragma unroll
  for (int j = 0; j < 4; ++j) { x0 += x1; x1 = (x1 << R1[j]) | (x1 >> (32 - R1[j])); x1 ^= x0; }
  x0 += K2; x1 += K0 + 2u;
  #pragma unroll
  for (int j = 0; j < 4; ++j) { x0 += x1; x1 = (x1 << R0[j]) | (x1 >> (32 - R0[j])); x1 ^= x0; }
  x0 += K0; x1 += K1 + 3u;
  #pragma unroll
  for (int j = 0; j < 4; ++j) { x0 += x1; x1 = (x1 << R1[j]) | (x1 >> (32 - R1[j])); x1 ^= x0; }
  x0 += K1; x1 += K2 + 4u;
  #pragma unroll
  for (int j = 0; j < 4; ++j) { x0 += x1; x1 = (x1 << R0[j]) | (x1 >> (32 - R0[j])); x1 ^= x0; }
  x0 += K2; x1 += K0 + 5u;
  o0 = x0; o1 = x1;
}

__device__ __forceinline__ double bits_to_gumbel_d(unsigned bits) {
  float f = __uint_as_float((bits >> 9) | 0x3f800000u) - 1.0f;   // exact in f32
  const double tiny = (double)1.17549435e-38f;
  double u = fmax(tiny, (double)f + tiny);
  return -log(-log(u));
}

__device__ __forceinline__ float rlane(float v, int l) {
  return __int_as_float(__builtin_amdgcn_readlane(__float_as_int(v), l));
}

// Barrier that waits LDS only (lgkmcnt(0)) — does NOT drain vmcnt, so global
// prefetch loads / fire-and-forget stores stay in flight across it.
// simm16 = vmcnt 63 (no wait: [3:0]=0xF,[15:14]=0x3), expcnt 7, lgkmcnt 0.
__device__ __forceinline__ void bar_lds() {
  __asm__ volatile("" ::: "memory");
  __builtin_amdgcn_s_waitcnt(0xC07F);
  __builtin_amdgcn_s_barrier();
  __asm__ volatile("" ::: "memory");
}

// ---------------- K0: pack/transpose weights ----------------
__global__ void k_transpose(const float* __restrict__ Wf, const float* __restrict__ Wb,
                            float* __restrict__ Wt) {
  int idx = blockIdx.x * 256 + threadIdx.x;     // < 66*4096
  int c = idx >> 12;                            // 0..65
  int k = idx & 4095;
  float v = (c < 64) ? Wf[(size_t)c * WFCOLS + k] : Wb[(size_t)(c - 64) * WBCOLS + k];
  Wt[(size_t)k * 68 + c] = v;
}

// ---------------- K1: big GEMM, k-split 4 -> partials ----------------
// 1024 blocks x 256 thr. block = (row-group of 64, k-quarter of 1024).
// X staged through LDS with coalesced dword loads (row stride 4111 floats is
// not 16B-aligned, so global loads are scalar; LDS row stride padded to 132
// floats -> ds_read_b128 start-banks 4*(lane+c)%32 tile all 32 banks,
// conflict-free). Wave w accumulates interleaved k-slices [w*32, w*32+32)
// of each 128-k tile; 4 wave-partials reduced in LDS (xs reused) at the end.
__global__ __launch_bounds__(256, 4) void k_gemm(const float* __restrict__ inp,
                                                 const float* __restrict__ Wt,
                                                 float* __restrict__ Pf,
                                                 double* __restrict__ Pd) {
  __shared__ __align__(16) float xs[64 * 132];   // 33.8 KB; aliased as red[2][64][65] for reduce
  __shared__ double redd[2][64][2];              // 2 KB
  int tid = threadIdx.x;
  int r = tid & 63;
  int w = __builtin_amdgcn_readfirstlane(tid >> 6);
  int rg = blockIdx.x >> 2, kq = blockIdx.x & 3;
  int rowbase = rg * 64;

  float acc[64];
  #pragma unroll
  for (int c = 0; c < 64; ++c) acc[c] = 0.f;
  double ad0 = 0.0, ad1 = 0.0;

  // staging indices (fixed across tiles): idx = tid + i*256 -> (row, 4-float group)
  int s_rr[8], s_c4[8];
  #pragma unroll
  for (int i = 0; i < 8; ++i) {
    int idx = tid + i * 256;
    s_rr[i] = idx >> 5;
    s_c4[i] = idx & 31;
  }

  for (int kt = 0; kt < 8; ++kt) {
    int kb = kq * 1024 + kt * 128;
    // ---- stage 64 rows x 128 k into LDS, coalesced ----
    #pragma unroll
    for (int i = 0; i < 8; ++i) {
      const float* g = inp + (size_t)(rowbase + s_rr[i]) * DIN + kb + s_c4[i] * 4;
      float4 v;
      v.x = g[0]; v.y = g[1]; v.z = g[2]; v.w = g[3];
      *(float4*)&xs[s_rr[i] * 132 + s_c4[i] * 4] = v;
    }
    __syncthreads();
    // ---- compute: wave w handles local k in [w*32, w*32+32) ----
    const float* wkbase = Wt + (size_t)(kb + w * 32) * 68;
    #pragma unroll
    for (int kk = 0; kk < 8; ++kk) {
      float4 xv = *(const float4*)&xs[r * 132 + w * 32 + kk * 4];
      #pragma unroll
      for (int j = 0; j < 4; ++j) {
        float x = (j == 0) ? xv.x : (j == 1) ? xv.y : (j == 2) ? xv.z : xv.w;
        const float* wp = wkbase + (size_t)(kk * 4 + j) * 68;   // wave-uniform -> scalar loads
        #pragma unroll
        for (int c = 0; c < 64; ++c) acc[c] = fmaf(x, wp[c], acc[c]);
        double xd = (double)x;
        ad0 = fma(xd, (double)wp[64], ad0);
        ad1 = fma(xd, (double)wp[65], ad1);
      }
    }
    __syncthreads();
  }

  // ---- cross-wave reduce (xs reused as red[2][64][65]) ----
  float* red = xs;
  if (w >= 2) {
    float* d = red + ((size_t)(w - 2) * 64 + r) * 65;
    #pragma unroll
    for (int c = 0; c < 64; ++c) d[c] = acc[c];
    redd[w - 2][r][0] = ad0; redd[w - 2][r][1] = ad1;
  }
  __syncthreads();
  if (w < 2) {
    const float* s = red + ((size_t)w * 64 + r) * 65;
    #pragma unroll
    for (int c = 0; c < 64; ++c) acc[c] += s[c];
    ad0 += redd[w][r][0]; ad1 += redd[w][r][1];
  }
  __syncthreads();
  if (w == 1) {
    float* d = red + (size_t)r * 65;
    #pragma unroll
    for (int c = 0; c < 64; ++c) d[c] = acc[c];
    redd[0][r][0] = ad0; redd[0][r][1] = ad1;
  }
  __syncthreads();
  if (w == 0) {
    const float* s = red + (size_t)r * 65;
    #pragma unroll
    for (int c = 0; c < 64; ++c) acc[c] += s[c];
    ad0 += redd[0][r][0]; ad1 += redd[0][r][1];
    int row = rowbase + r;
    float* po = Pf + (size_t)kq * NROWS * 64 + (size_t)row * 64;
    #pragma unroll
    for (int c = 0; c < 64; ++c) po[c] = acc[c];
    Pd[(size_t)kq * NROWS * 2 + (size_t)row * 2 + 0] = ad0;
    Pd[(size_t)kq * NROWS * 2 + (size_t)row * 2 + 1] = ad1;
  }
}

// ---------------- K1b: reduce the 4 k-quarter partials ----------------
__global__ void k_reduce(const float* __restrict__ Pf, const double* __restrict__ Pd,
                         float* __restrict__ Xf, double* __restrict__ Xb) {
  size_t gid = (size_t)blockIdx.x * 256 + threadIdx.x;
  const size_t NF = (size_t)NROWS * 64;
  if (gid < NF) {
    Xf[gid] = (Pf[gid] + Pf[NF + gid]) + (Pf[2 * NF + gid] + Pf[3 * NF + gid]);
  } else if (gid < NF + (size_t)NROWS * 2) {
    size_t j = gid - NF;
    const size_t ND = (size_t)NROWS * 2;
    Xb[j] = (Pd[j] + Pd[ND + j]) + (Pd[2 * ND + j] + Pd[3 * ND + j]);
  }
}

// ---------------- K2: gumbel noise (JAX partitionable threefry), FP64 ----------------
__global__ void k_noise(double* __restrict__ Gg, double* __restrict__ Gb) {
  int t = blockIdx.x, tid = threadIdx.x;
  unsigned a, b, k1a, k1b, k2a, k2b, o0, o1;
  tf2x32(0u, 42u, 0u, (unsigned)t, a, b);      // keys[t] = split(key(42),128)[t]
  tf2x32(a, b, 0u, 0u, k1a, k1b);              // k1
  tf2x32(a, b, 0u, 1u, k2a, k2b);              // k2
  for (int i = tid; i < NB * NG; i += 256) {
    tf2x32(k1a, k1b, 0u, (unsigned)i, o0, o1);
    Gg[(size_t)t * NB * NG + i] = bits_to_gumbel_d(o0 ^ o1);
  }
  {
    int i = tid;                               // NB*2 == 256 == blockDim
    tf2x32(k2a, k2b, 0u, (unsigned)i, o0, o1);
    Gb[(size_t)t * NB * 2 + i] = bits_to_gumbel_d(o0 ^ o1);
  }
}

// ---------------- K3: sequential scan, one block per batch row ----------------
// wave0 owns all state; waves 1-3 compute only gi. 2 LDS-only barriers/step.
__global__ __launch_bounds__(256) void k_scan(
    const float* __restrict__ inp, const float* __restrict__ hx,
    const float* __restrict__ Wf, const float* __restrict__ bf,
    const float* __restrict__ Wih, const float* __restrict__ bih,
    const float* __restrict__ bhh, const float* __restrict__ Wc,
    const float* __restrict__ bc, const float* __restrict__ Wl,
    const float* __restrict__ bl, const float* __restrict__ Wpi,
    const float* __restrict__ bpi, const float* __restrict__ Wb,
    const float* __restrict__ bb,
    const float* __restrict__ Xf, const double* __restrict__ Xb,
    const double* __restrict__ Gg, const double* __restrict__ Gb,
    float* __restrict__ lgst, float* __restrict__ lbst,
    int* __restrict__ gidxst, int* __restrict__ bidxst,
    float* __restrict__ out) {
  const int n = blockIdx.x;
  const int tid = threadIdx.x;
  const int lane = tid & 63;
  const int w = __builtin_amdgcn_readfirstlane(tid >> 6);

  __shared__ float s_lds[64], h_lds[64], gi_lds[192];
  __shared__ int nz_sh;

  // ---- waves 1..3: register-resident Wih rows ----
  float wih_r[128];
  float bih_r = 0.f;
  if (w != 0) {
    int m = tid - 64;
    #pragma unroll
    for (int k = 0; k < 128; ++k) wih_r[k] = Wih[(size_t)m * 128 + k];
    bih_r = bih[m];
  }

  // ---- wave0 state & constants ----
  float wfs[29], wpi0[78], wpi1[78], mtr[5];
  float bf_r = 0, bhr_r = 0, bhz_r = 0, bhn_r = 0;
  float wc0 = 0, wc1 = 0, wl0 = 0, wl1 = 0, wl2 = 0;
  float bl0 = 0, bl1 = 0, bl2 = 0, bc0 = 0, bpi0 = 0, bpi1 = 0;
  float wbs0 = 0, wbs1 = 0;
  float hreg = 0.f, rgbp = 0.f, xf = 0.f;
  double S0 = 0.0, S1 = 0.0, bb0d = 0.0, bb1d = 0.0;
  double gum0 = 0.0, gum1 = 0.0, xb0 = 0.0, xb1 = 0.0, gb0 = 0.0, gb1 = 0.0;
  int dsto = -1;

  if (tid == 0) nz_sh = 0;
  __syncthreads();
  {
    int any = 0;
    const float4* h4 = (const float4*)hx;
    for (int i = tid; i < (NB * STATE) / 4; i += 256) {
      float4 v = h4[i];
      any |= (v.x != 0.f) | (v.y != 0.f) | (v.z != 0.f) | (v.w != 0.f);
    }
    if (any) nz_sh = 1;
  }
  if (w == 0) {
    #pragma unroll
    for (int k = 0; k < 29; ++k) wfs[k] = Wf[(size_t)lane * WFCOLS + CONVOUT + k];
    #pragma unroll
    for (int k = 0; k < 78; ++k) wpi0[k] = Wpi[(size_t)lane * 78 + k];
    bpi0 = bpi[lane];
    if (lane < 26) {
      #pragma unroll
      for (int k = 0; k < 78; ++k) wpi1[k] = Wpi[(size_t)(64 + lane) * 78 + k];
      bpi1 = bpi[64 + lane];
    }
    bf_r = bf[lane];
    bhr_r = bhh[lane]; bhz_r = bhh[64 + lane]; bhn_r = bhh[128 + lane];
    wc0 = Wc[lane]; wc1 = Wc[64 + lane]; bc0 = bc[0];
    wl0 = Wl[lane]; wl1 = Wl[64 + lane]; wl2 = Wl[128 + lane];
    bl0 = bl[0]; bl1 = bl[1]; bl2 = bl[2];
    bb0d = (double)bb[0]; bb1d = (double)bb[1];
    if (lane < 14) { wbs0 = Wb[CONVOUT + lane]; wbs1 = Wb[(size_t)WBCOLS + CONVOUT + lane]; }
    const float* r0 = inp + (size_t)n * DIN + CONVOUT;
    #pragma unroll
    for (int k = 0; k < 5; ++k) {
      int ttv = (int)r0[k], cntv = (int)r0[5 + k] - 1, objv = (int)r0[10 + k];
      float v = 0.f;
      if (lane < 5)       v = (lane == ttv) ? 1.f : 0.f;
      else if (lane < 8)  v = ((lane - 5) == cntv) ? 1.f : 0.f;
      else if (lane < 14) v = ((lane - 8) == objv) ? 1.f : 0.f;
      mtr[k] = v;
    }
    // packed state layout: lanes 0-13 r, 14-27 g, 28 b, 29-33 p
    int src = -1;
    if (lane < 14)       { dsto = 5 + lane;          src = dsto; }
    else if (lane < 28)  { dsto = 83 + (lane - 14);  src = dsto; }
    else if (lane == 28) { dsto = 97;                src = 97; }
    else if (lane < 34)  { dsto = lane - 29;         src = dsto; }
    rgbp = (src >= 0) ? hx[(size_t)n * STATE + src] : 0.f;
    hreg = hx[(size_t)n * STATE + 19 + lane];
  }
  __syncthreads();   // nz_sh ready
  if (w == 0) {
    if (nz_sh == 0) {   // new episode (hx all zero): p[0]=1, r=g=M[:,0]
      const float* r0 = inp + (size_t)n * DIN + CONVOUT;
      int tt0 = (int)r0[0], cnt0 = (int)r0[5] - 1, obj0 = (int)r0[10];
      if (lane == 29) rgbp = 1.f;
      else if (lane < 14) rgbp = mtr[0];
      else if (lane >= 14 && lane < 28) {
        int j = lane - 14;
        rgbp = (j < 5) ? ((j == tt0) ? 1.f : 0.f)
             : (j < 8) ? (((j - 5) == cnt0) ? 1.f : 0.f)
                       : (((j - 8) == obj0) ? 1.f : 0.f);
      }
    }
    // S recurrence init: S = dot(g0, Wbs) fp64
    #pragma unroll
    for (int j = 0; j < 14; ++j) {
      double gv = (double)rlane(rgbp, 14 + j);
      S0 += gv * (double)rlane(wbs0, j);
      S1 += gv * (double)rlane(wbs1, j);
    }
    h_lds[lane] = hreg;    // publish h(0)
    // t=0 data
    gum0 = Gg[(size_t)n * NG + lane];
    gum1 = (lane < 26) ? Gg[(size_t)n * NG + 64 + lane] : 0.0;
    xf = Xf[(size_t)n * 64 + lane];
    xb0 = Xb[(size_t)n * 2 + 0]; xb1 = Xb[(size_t)n * 2 + 1];
    gb0 = Gb[(size_t)n * 2 + 0]; gb1 = Gb[(size_t)n * 2 + 1];
  }
  __syncthreads();

  const size_t outF = (size_t)T_STEPS * NB * STATE;

  #pragma unroll 1
  for (int t = 0; t < T_STEPS; ++t) {
    float sv_own = 0.f, cg = 0.f, accR0 = 0.f, accR1 = 0.f;
    double cgd = 0.0;

    if (w == 0) {
      // s = xf + bf + Wf_state . [r,g,b]   (rgb packed in lanes 0..28)
      float acc = xf + bf_r;
      #pragma unroll
      for (int k = 0; k < 29; ++k) acc = fmaf(wfs[k], rlane(rgbp, k), acc);
      sv_own = acc;
      s_lds[lane] = acc;
    }
    bar_lds();   // ---- bar_s: s (and h from prev step) published ----

    if (w == 0) {
      // ---- slack work (runs concurrent with waves1-3 gi) ----
      float p0 = wl0 * hreg, p1 = wl1 * hreg, p2 = wl2 * hreg;
      float cga = fmaf(wc1, hreg, wc0 * sv_own);
      #pragma unroll
      for (int off = 32; off; off >>= 1) {
        p0 += __shfl_xor(p0, off, 64);
        p1 += __shfl_xor(p1, off, 64);
        p2 += __shfl_xor(p2, off, 64);
        cga += __shfl_xor(cga, off, 64);
      }
      p0 += bl0; p1 += bl1; p2 += bl2;
      float mx = fmaxf(p0, fmaxf(p1, p2));
      float e0 = expf(p0 - mx), e1 = expf(p1 - mx), e2 = expf(p2 - mx);
      float se = e0 + e1 + e2;
      float l0 = e0 / se, l1 = e1 / se, l2 = e2 / se;
      cg = 1.f / (1.f + expf(-(cga + bc0)));
      cgd = (double)cg;
      // pconv: p values are uniform via readlane
      float pv0 = rlane(rgbp, 29), pv1 = rlane(rgbp, 30), pv2 = rlane(rgbp, 31);
      float pv3 = rlane(rgbp, 32), pv4 = rlane(rgbp, 33);
      float pc0 = pv0 * l1 + pv1 * l2;
      float pc1 = pv0 * l0 + pv1 * l1 + pv2 * l2;
      float pc2 = pv1 * l0 + pv2 * l1 + pv3 * l2;
      float pc3 = pv2 * l0 + pv3 * l1 + pv4 * l2;
      float pc4 = pv3 * l0 + pv4 * l1;
      // p update (lanes 29-33), r update (lanes 0-13)
      if (lane >= 29 && lane < 34) {
        float pcl = (lane == 29) ? pc0 : (lane == 30) ? pc1 : (lane == 31) ? pc2
                  : (lane == 32) ? pc3 : pc4;
        rgbp = cg * pcl + (1.f - cg) * rgbp;
      }
      if (lane < 14) {
        float rn = pc0 * mtr[0] + pc1 * mtr[1] + pc2 * mtr[2] + pc3 * mtr[3] + pc4 * mtr[4];
        rgbp = cg * rn + (1.f - cg) * rgbp;
      }
      // lg r-part (uses new r)
      #pragma unroll
      for (int k = 0; k < 14; ++k) {
        float rv = rlane(rgbp, k);
        accR0 = fmaf(wpi0[64 + k], rv, accR0);
        accR1 = fmaf(wpi1[64 + k], rv, accR1);
      }
    } else {
      // ---- waves 1..3: gi = Wih . [s, h] + bih ----
      float sv = s_lds[lane];
      float hv = h_lds[lane];
      float acc = bih_r;
      #pragma unroll
      for (int k = 0; k < 64; ++k) acc = fmaf(wih_r[k], rlane(sv, k), acc);
      #pragma unroll
      for (int k = 0; k < 64; ++k) acc = fmaf(wih_r[64 + k], rlane(hv, k), acc);
      gi_lds[tid - 64] = acc;
    }
    bar_lds();   // ---- bar_gi ----

    if (w == 0) {
      // prefetch t+1 inputs now; they drain at next bar_s (~full step of slack)
      int tn = (t + 1 < T_STEPS) ? t + 1 : t;
      double gum0n = Gg[(size_t)tn * NB * NG + (size_t)n * NG + lane];
      double gum1n = (lane < 26) ? Gg[(size_t)tn * NB * NG + (size_t)n * NG + 64 + lane] : 0.0;
      float xfn = Xf[((size_t)tn * NB + n) * 64 + lane];
      double xb0n = Xb[((size_t)tn * NB + n) * 2 + 0];
      double xb1n = Xb[((size_t)tn * NB + n) * 2 + 1];
      double gb0n = Gb[((size_t)tn * NB + n) * 2 + 0];
      double gb1n = Gb[((size_t)tn * NB + n) * 2 + 1];

      // gates + h update
      float g0 = gi_lds[lane], g1 = gi_lds[64 + lane], g2 = gi_lds[128 + lane];
      float rg = 1.f / (1.f + expf(-(g0 + bhr_r)));
      float z  = 1.f / (1.f + expf(-(g1 + bhz_r)));
      float nn = tanhf(g2 + rg * bhn_r);
      float hnew = (1.f - z) * nn;
      hreg = cg * hnew + (1.f - cg) * hreg;

      // lg (fp32 fast path)
      float a0 = bpi0 + accR0, a1 = bpi1 + accR1;
      #pragma unroll
      for (int k = 0; k < 64; ++k) {
        float hv2 = rlane(hreg, k);
        a0 = fmaf(wpi0[k], hv2, a0);
        a1 = fmaf(wpi1[k], hv2, a1);
      }
      const float NEGINF = -3.0e38f;
      float vb0 = (float)(gum0 + (double)a0);
      float vb1 = (lane < 26) ? (float)(gum1 + (double)a1) : NEGINF;
      // butterfly argmax carrying (m1, idx, m2) for margin check
      float m1, m2; int idx;
      if (vb1 > vb0) { m1 = vb1; idx = lane + 64; m2 = vb0; }
      else           { m1 = vb0; idx = lane;      m2 = vb1; }
      #pragma unroll
      for (int off = 32; off; off >>= 1) {
        float o1 = __shfl_xor(m1, off, 64);
        int   oi = __shfl_xor(idx, off, 64);
        float o2 = __shfl_xor(m2, off, 64);
        bool take = (o1 > m1) || (o1 == m1 && oi < idx);
        float base2 = take ? m1 : m2;
        float oth   = take ? o2 : o1;
        m2 = fmaxf(base2, oth);
        if (take) { m1 = o1; idx = oi; }
      }
      int gidx = idx;
      if (m1 - m2 < 3e-5f) {
        // rare fp64 slow path: exact recompute, weights from global
        double e0d = (double)bpi0;
        double e1d = (lane < 26) ? (double)bpi1 : -1.0e300;
        #pragma unroll 1
        for (int k = 0; k < 64; ++k) {
          double hv2 = (double)rlane(hreg, k);
          e0d = fma((double)Wpi[(size_t)lane * 78 + k], hv2, e0d);
          if (lane < 26) e1d = fma((double)Wpi[(size_t)(64 + lane) * 78 + k], hv2, e1d);
        }
        #pragma unroll 1
        for (int k = 0; k < 14; ++k) {
          double rv = (double)rlane(rgbp, k);
          e0d = fma((double)Wpi[(size_t)lane * 78 + 64 + k], rv, e0d);
          if (lane < 26) e1d = fma((double)Wpi[(size_t)(64 + lane) * 78 + 64 + k], rv, e1d);
        }
        double kk0 = e0d + gum0;
        double kk1 = (lane < 26) ? e1d + gum1 : -1.0e300;
        double d1; int di;
        if (kk1 > kk0) { d1 = kk1; di = lane + 64; } else { d1 = kk0; di = lane; }
        #pragma unroll
        for (int off = 32; off; off >>= 1) {
          double od = __shfl_xor(d1, off, 64);
          int    oi = __shfl_xor(di, off, 64);
          if (od > d1 || (od == d1 && oi < di)) { d1 = od; di = oi; }
        }
        gidx = di;
      }
      // g update from sampled embedding
      int t1 = gidx / 18, rem = gidx - t1 * 18;
      int b1 = rem / 6, c1 = rem - b1 * 6;
      if (lane >= 14 && lane < 28) {
        int j = lane - 14;
        float ge = (j < 5) ? ((j == t1) ? 1.f : 0.f)
                 : (j < 8) ? (((j - 5) == b1) ? 1.f : 0.f)
                           : (((j - 8) == c1) ? 1.f : 0.f);
        rgbp = cg * ge + (1.f - cg) * rgbp;
      }
      // b sample via fp64 scalar recurrence S = dot(g, Wbs)
      double u0 = (double)rlane(wbs0, t1) + (double)rlane(wbs0, 5 + b1) + (double)rlane(wbs0, 8 + c1);
      double u1 = (double)rlane(wbs1, t1) + (double)rlane(wbs1, 5 + b1) + (double)rlane(wbs1, 8 + c1);
      S0 = cgd * u0 + (1.0 - cgd) * S0;
      S1 = cgd * u1 + (1.0 - cgd) * S1;
      double lb0 = xb0 + bb0d + S0;
      double lb1 = xb1 + bb1d + S1;
      int bi = ((lb1 + gb1) > (lb0 + gb0)) ? 1 : 0;
      if (lane == 28) rgbp = (float)bi;

      // stores (fire-and-forget; barriers never drain vmcnt)
      size_t rn = (size_t)t * NB + n;
      float* ob = out + rn * STATE;
      if (dsto >= 0) ob[dsto] = rgbp;
      ob[19 + lane] = hreg;
      lgst[rn * NG + lane] = a0;
      if (lane < 26) lgst[rn * NG + 64 + lane] = a1;
      if (lane == 0) {
        lbst[rn * 2 + 0] = (float)lb0; lbst[rn * 2 + 1] = (float)lb1;
        gidxst[rn] = gidx; bidxst[rn] = bi;
      }
      if (t == T_STEPS - 1) {
        float* of = out + outF + (size_t)n * STATE;
        if (dsto >= 0) of[dsto] = rgbp;
        of[19 + lane] = hreg;
      }
      // publish h for next step, rotate prefetched data
      h_lds[lane] = hreg;
      gum0 = gum0n; gum1 = gum1n; xf = xfn;
      xb0 = xb0n; xb1 = xb1n; gb0 = gb0n; gb1 = gb1n;
    }
  }
}

// ---------------- K4: deferred log-prob (fp32, fully parallel) ----------------
__global__ __launch_bounds__(256) void k_lp(const float* __restrict__ lgst,
                                            const float* __restrict__ lbst,
                                            const int* __restrict__ gidxst,
                                            const int* __restrict__ bidxst,
                                            float* __restrict__ out) {
  int tid = threadIdx.x, lane = tid & 63, w = tid >> 6;
  size_t rn = (size_t)blockIdx.x * 4 + w;   // < 16384
  const float* lg = lgst + rn * NG;
  float v0 = lg[lane];
  float v1 = (lane < 26) ? lg[64 + lane] : -3.0e38f;
  float ml = fmaxf(v0, v1);
  #pragma unroll
  for (int off = 32; off; off >>= 1) ml = fmaxf(ml, __shfl_xor(ml, off, 64));
  float e = expf(v0 - ml) + ((lane < 26) ? expf(v1 - ml) : 0.f);
  #pragma unroll
  for (int off = 32; off; off >>= 1) e += __shfl_xor(e, off, 64);
  int gi = gidxst[rn];
  float lpg = (lg[gi] - ml) - logf(e);
  float lb0 = lbst[rn * 2 + 0], lb1 = lbst[rn * 2 + 1];
  int bi = bidxst[rn];
  float mx = fmaxf(lb0, lb1);
  float seb = expf(lb0 - mx) + expf(lb1 - mx);
  float lpb = ((bi ? lb1 : lb0) - mx) - logf(seb);
  if (lane == 0) {
    int t = (int)(rn / NB), n = (int)(rn % NB);
    float lp = lpg + lpb;
    out[rn * STATE + 98] = lp;
    if (t == T_STEPS - 1) out[(size_t)T_STEPS * NB * STATE + (size_t)n * STATE + 98] = lp;
  }
}

// ---------------- launcher ----------------
extern "C" void kernel_launch(void* const* d_in, const int* in_sizes, int n_in,
                              void* d_out, int out_size, void* d_ws, size_t ws_size,
                              hipStream_t stream) {
  const float* inp = (const float*)d_in[0];
  const float* hx  = (const float*)d_in[1];
  const float* Wf  = (const float*)d_in[2];
  const float* bf  = (const float*)d_in[3];
  const float* Wih = (const float*)d_in[4];
  const float* bih = (const float*)d_in[5];
  const float* bhh = (const float*)d_in[6];
  const float* Wc  = (const float*)d_in[7];
  const float* bc  = (const float*)d_in[8];
  const float* Wl  = (const float*)d_in[9];
  const float* bl  = (const float*)d_in[10];
  const float* Wpi = (const float*)d_in[11];
  const float* bpi = (const float*)d_in[12];
  const float* Wb  = (const float*)d_in[13];
  const float* bb  = (const float*)d_in[14];
  float* out = (float*)d_out;

  // ws layout (doubles first for alignment), total ~35.5 MB:
  double* Gg = (double*)d_ws;                       // 128*128*90
  double* Gb = Gg + (size_t)T_STEPS * NB * NG;      // 128*128*2
  double* Xb = Gb + (size_t)T_STEPS * NB * 2;       // 16384*2
  double* Pd = Xb + (size_t)NROWS * 2;              // 4*16384*2
  float*  Wt = (float*)(Pd + (size_t)4 * NROWS * 2);// 4096*68
  float*  Xf = Wt + (size_t)4096 * 68;              // 16384*64
  float*  Pf = Xf + (size_t)NROWS * 64;             // 4*16384*64 (16.8 MB)
  // aliased onto Pf (consumed by k_reduce before k_scan writes these):
  float*  lgst = Pf;                                // 16384*90
  float*  lbst = lgst + (size_t)NROWS * NG;         // 16384*2
  int*    gidxst = (int*)(lbst + (size_t)NROWS * 2);// 16384
  int*    bidxst = gidxst + NROWS;                  // 16384

  k_transpose<<<(66 * 4096) / 256, 256, 0, stream>>>(Wf, Wb, Wt);
  k_gemm<<<1024, 256, 0, stream>>>(inp, Wt, Pf, Pd);
  {
    size_t tot = (size_t)NROWS * 64 + (size_t)NROWS * 2;
    k_reduce<<<(int)((tot + 255) / 256), 256, 0, stream>>>(Pf, Pd, Xf, Xb);
  }
  k_noise<<<T_STEPS, 256, 0, stream>>>(Gg, Gb);
  k_scan<<<NB, 256, 0, stream>>>(inp, hx, Wf, bf, Wih, bih, bhh, Wc, bc, Wl, bl,
                                 Wpi, bpi, Wb, bb, Xf, Xb, Gg, Gb,
                                 lgst, lbst, gidxst, bidxst, out);
  k_lp<<<NROWS / 4, 256, 0, stream>>>(lgst, lbst, gidxst, bidxst, out);
}

// Round 3
// 834.353 us; speedup vs baseline: 1.6468x; 1.1542x over previous
//
#include <hip/hip_runtime.h>
#include <stdint.h>
#include <math.h>

// Problem constants (from reference)
#define T_STEPS 128
#define NB      128
#define HID     64
#define CONVOUT 4096
#define NSUB    5
#define SUBSZ   14      // A+B+C = 5+3+6
#define NG      90      // A*B*C
#define STATE   99
#define DIN     4111    // CONVOUT + 3*NSUB
#define WFCOLS  4125    // CONVOUT + 2*SUBSZ + 1
#define WBCOLS  4110    // CONVOUT + SUBSZ
#define NROWS   (T_STEPS * NB)   // 16384

#define NEGINFF (-3.0e38f)

typedef __attribute__((ext_vector_type(2))) float f32x2;

// ---------------- Threefry-2x32 (JAX-compatible) ----------------
__device__ __forceinline__ void tf2x32(unsigned k0, unsigned k1,
                                       unsigned x0, unsigned x1,
                                       unsigned &o0, unsigned &o1) {
  unsigned K0 = k0, K1 = k1, K2 = k0 ^ k1 ^ 0x1BD11BDAu;
  x0 += K0; x1 += K1;
  const int R0[4] = {13, 15, 26, 6};
  const int R1[4] = {17, 29, 16, 24};
  #pragma unroll
  for (int j = 0; j < 4; ++j) { x0 += x1; x1 = (x1 << R0[j]) | (x1 >> (32 - R0[j])); x1 ^= x0; }
  x0 += K1; x1 += K2 + 1u;
  #pragma unroll
  for (int j = 0; j < 4; ++j) { x0 += x1; x1 = (x1 << R1[j]) | (x1 >> (32 - R1[j])); x1 ^= x0; }
  x0 += K2; x1 += K0 + 2u;
  #pragma unroll
  for (int j = 0; j < 4; ++j) { x0 += x1; x1 = (x1 << R0[j]) | (x1 >> (32 - R0[j])); x1 ^= x0; }
  x0 += K0; x1 += K1 + 3u;
  #pragma unroll
  for (int j = 0; j < 4; ++j) { x0 += x1; x1 = (x1 << R1[j]) | (x1 >> (32 - R1[j])); x1 ^= x0; }
  x0 += K1; x1 += K2 + 4u;
  #pragma unroll
  for (int j = 0; j < 4; ++j) { x0 += x1; x1 = (x1 << R0[j]) | (x1 >> (32 - R0[j])); x1 ^= x0; }
  x0 += K2; x1 += K0 + 5u;
  o0 = x0; o1 = x1;
}

__device__ __forceinline__ double bits_to_gumbel_d(unsigned bits) {
  float f = __uint_as_float((bits >> 9) | 0x3f800000u) - 1.0f;   // exact in f32
  const double tiny = (double)1.17549435e-38f;
  double u = fmax(tiny, (double)f + tiny);
  return -log(-log(u));
}

__device__ __forceinline__ float rlane(float v, int l) {
  return __int_as_float(__builtin_amdgcn_readlane(__float_as_int(v), l));
}

// DPP shifted copy: lanes without a source (or rows masked off) get `fill`.
template<int CTRL, int RM>
__device__ __forceinline__ float dpp_mv(float x, float fill) {
  return __int_as_float(__builtin_amdgcn_update_dpp(
      __float_as_int(fill), __float_as_int(x), CTRL, RM, 0xF, false));
}

// Barrier that waits LDS only (lgkmcnt(0)) — does NOT drain vmcnt, so global
// prefetch loads / fire-and-forget stores stay in flight across it.
__device__ __forceinline__ void bar_lds() {
  __asm__ volatile("" ::: "memory");
  __builtin_amdgcn_s_waitcnt(0xC07F);
  __builtin_amdgcn_s_barrier();
  __asm__ volatile("" ::: "memory");
}

// ---------------- K0: pack/transpose weights ----------------
__global__ void k_transpose(const float* __restrict__ Wf, const float* __restrict__ Wb,
                            float* __restrict__ Wt) {
  int idx = blockIdx.x * 256 + threadIdx.x;     // < 66*4096
  int c = idx >> 12;                            // 0..65
  int k = idx & 4095;
  float v = (c < 64) ? Wf[(size_t)c * WFCOLS + k] : Wb[(size_t)(c - 64) * WBCOLS + k];
  Wt[(size_t)k * 68 + c] = v;
}

// ---------------- K1: big GEMM, k-split 4 -> partials ----------------
__global__ __launch_bounds__(256, 4) void k_gemm(const float* __restrict__ inp,
                                                 const float* __restrict__ Wt,
                                                 float* __restrict__ Pf,
                                                 double* __restrict__ Pd) {
  __shared__ __align__(16) float xs[64 * 132];   // 33.8 KB; aliased as red[2][64][65] for reduce
  __shared__ double redd[2][64][2];              // 2 KB
  int tid = threadIdx.x;
  int r = tid & 63;
  int w = __builtin_amdgcn_readfirstlane(tid >> 6);
  int rg = blockIdx.x >> 2, kq = blockIdx.x & 3;
  int rowbase = rg * 64;

  float acc[64];
  #pragma unroll
  for (int c = 0; c < 64; ++c) acc[c] = 0.f;
  double ad0 = 0.0, ad1 = 0.0;

  int s_rr[8], s_c4[8];
  #pragma unroll
  for (int i = 0; i < 8; ++i) {
    int idx = tid + i * 256;
    s_rr[i] = idx >> 5;
    s_c4[i] = idx & 31;
  }

  for (int kt = 0; kt < 8; ++kt) {
    int kb = kq * 1024 + kt * 128;
    #pragma unroll
    for (int i = 0; i < 8; ++i) {
      const float* g = inp + (size_t)(rowbase + s_rr[i]) * DIN + kb + s_c4[i] * 4;
      float4 v;
      v.x = g[0]; v.y = g[1]; v.z = g[2]; v.w = g[3];
      *(float4*)&xs[s_rr[i] * 132 + s_c4[i] * 4] = v;
    }
    __syncthreads();
    const float* wkbase = Wt + (size_t)(kb + w * 32) * 68;
    #pragma unroll
    for (int kk = 0; kk < 8; ++kk) {
      float4 xv = *(const float4*)&xs[r * 132 + w * 32 + kk * 4];
      #pragma unroll
      for (int j = 0; j < 4; ++j) {
        float x = (j == 0) ? xv.x : (j == 1) ? xv.y : (j == 2) ? xv.z : xv.w;
        const float* wp = wkbase + (size_t)(kk * 4 + j) * 68;
        #pragma unroll
        for (int c = 0; c < 64; ++c) acc[c] = fmaf(x, wp[c], acc[c]);
        double xd = (double)x;
        ad0 = fma(xd, (double)wp[64], ad0);
        ad1 = fma(xd, (double)wp[65], ad1);
      }
    }
    __syncthreads();
  }

  float* red = xs;
  if (w >= 2) {
    float* d = red + ((size_t)(w - 2) * 64 + r) * 65;
    #pragma unroll
    for (int c = 0; c < 64; ++c) d[c] = acc[c];
    redd[w - 2][r][0] = ad0; redd[w - 2][r][1] = ad1;
  }
  __syncthreads();
  if (w < 2) {
    const float* s = red + ((size_t)w * 64 + r) * 65;
    #pragma unroll
    for (int c = 0; c < 64; ++c) acc[c] += s[c];
    ad0 += redd[w][r][0]; ad1 += redd[w][r][1];
  }
  __syncthreads();
  if (w == 1) {
    float* d = red + (size_t)r * 65;
    #pragma unroll
    for (int c = 0; c < 64; ++c) d[c] = acc[c];
    redd[0][r][0] = ad0; redd[0][r][1] = ad1;
  }
  __syncthreads();
  if (w == 0) {
    const float* s = red + (size_t)r * 65;
    #pragma unroll
    for (int c = 0; c < 64; ++c) acc[c] += s[c];
    ad0 += redd[0][r][0]; ad1 += redd[0][r][1];
    int row = rowbase + r;
    float* po = Pf + (size_t)kq * NROWS * 64 + (size_t)row * 64;
    #pragma unroll
    for (int c = 0; c < 64; ++c) po[c] = acc[c];
    Pd[(size_t)kq * NROWS * 2 + (size_t)row * 2 + 0] = ad0;
    Pd[(size_t)kq * NROWS * 2 + (size_t)row * 2 + 1] = ad1;
  }
}

// ---------------- K1b: reduce the 4 k-quarter partials ----------------
__global__ void k_reduce(const float* __restrict__ Pf, const double* __restrict__ Pd,
                         float* __restrict__ Xf, double* __restrict__ Xb) {
  size_t gid = (size_t)blockIdx.x * 256 + threadIdx.x;
  const size_t NF = (size_t)NROWS * 64;
  if (gid < NF) {
    Xf[gid] = (Pf[gid] + Pf[NF + gid]) + (Pf[2 * NF + gid] + Pf[3 * NF + gid]);
  } else if (gid < NF + (size_t)NROWS * 2) {
    size_t j = gid - NF;
    const size_t ND = (size_t)NROWS * 2;
    Xb[j] = (Pd[j] + Pd[ND + j]) + (Pd[2 * ND + j] + Pd[3 * ND + j]);
  }
}

// ---------------- K2: gumbel noise (JAX partitionable threefry), FP64 ----------------
__global__ void k_noise(double* __restrict__ Gg, double* __restrict__ Gb) {
  int t = blockIdx.x, tid = threadIdx.x;
  unsigned a, b, k1a, k1b, k2a, k2b, o0, o1;
  tf2x32(0u, 42u, 0u, (unsigned)t, a, b);
  tf2x32(a, b, 0u, 0u, k1a, k1b);
  tf2x32(a, b, 0u, 1u, k2a, k2b);
  for (int i = tid; i < NB * NG; i += 256) {
    tf2x32(k1a, k1b, 0u, (unsigned)i, o0, o1);
    Gg[(size_t)t * NB * NG + i] = bits_to_gumbel_d(o0 ^ o1);
  }
  {
    int i = tid;
    tf2x32(k2a, k2b, 0u, (unsigned)i, o0, o1);
    Gb[(size_t)t * NB * 2 + i] = bits_to_gumbel_d(o0 ^ o1);
  }
}

// ---------------- K3: sequential scan, one block per batch row ----------------
// wave0 owns all state; waves 1-3 compute gi via uniform ds_read_b64 broadcast
// pairs (no readlane chains). Low-rank recurrences (R_s, G_s, accR) remove the
// s-GEMV and lg r-part. Cross-lane reductions via DPP (row_shr/bcast to lane63).
__global__ __launch_bounds__(256) void k_scan(
    const float* __restrict__ inp, const float* __restrict__ hx,
    const float* __restrict__ Wf, const float* __restrict__ bf,
    const float* __restrict__ Wih, const float* __restrict__ bih,
    const float* __restrict__ bhh, const float* __restrict__ Wc,
    const float* __restrict__ bc, const float* __restrict__ Wl,
    const float* __restrict__ bl, const float* __restrict__ Wpi,
    const float* __restrict__ bpi, const float* __restrict__ Wb,
    const float* __restrict__ bb,
    const float* __restrict__ Xf, const double* __restrict__ Xb,
    const double* __restrict__ Gg, const double* __restrict__ Gb,
    float* __restrict__ lgst, float* __restrict__ lbst,
    int* __restrict__ gidxst, int* __restrict__ bidxst,
    float* __restrict__ out) {
  const int n = blockIdx.x;
  const int tid = threadIdx.x;
  const int lane = tid & 63;
  const int w = __builtin_amdgcn_readfirstlane(tid >> 6);

  __shared__ __align__(16) float sh_lds[128];   // [0:64)=s, [64:128)=h
  __shared__ float gi_lds[192];
  __shared__ int nz_sh;

  // ---- waves 1..3: register-resident Wih rows as pairs ----
  f32x2 wih_p[64];
  float bih_r = 0.f;
  if (w != 0) {
    int m = tid - 64;
    const f32x2* wrow = (const f32x2*)&Wih[(size_t)m * 128];
    #pragma unroll
    for (int k2 = 0; k2 < 64; ++k2) wih_p[k2] = wrow[k2];
    bih_r = bih[m];
  }

  // ---- wave0 state & constants ----
  f32x2 wpi0_p[32], wpi1_p[32];
  float wfsg[14], mtr[5], WfrM[5], WpiM0[5], WpiM1[5];
  float wfs28 = 0.f;
  float bf_r = 0, bhr_r = 0, bhz_r = 0, bhn_r = 0;
  float wc0 = 0, wc1 = 0, wl0 = 0, wl1 = 0, wl2 = 0;
  float bl0 = 0, bl1 = 0, bl2 = 0, bc0 = 0, bpi0 = 0, bpi1 = 0;
  float wbs0 = 0, wbs1 = 0;
  float hreg = 0.f, rgbp = 0.f;
  float sv_own = 0.f, R_s = 0.f, G_s = 0.f;
  float accR0_run = 0.f, accR1_run = 0.f;
  float xfp = 0.f;
  double S0 = 0.0, S1 = 0.0, bb0d = 0.0, bb1d = 0.0;
  double gum0 = 0.0, gum1 = 0.0, xb0 = 0.0, xb1 = 0.0, gb0 = 0.0, gb1 = 0.0;
  int dsto = -1;

  #pragma unroll
  for (int k = 0; k < 5; ++k) { mtr[k] = 0.f; WfrM[k] = 0.f; WpiM0[k] = 0.f; WpiM1[k] = 0.f; }
  #pragma unroll
  for (int k = 0; k < 14; ++k) wfsg[k] = 0.f;

  if (tid == 0) nz_sh = 0;
  __syncthreads();
  {
    int any = 0;
    const float4* h4 = (const float4*)hx;
    for (int i = tid; i < (NB * STATE) / 4; i += 256) {
      float4 v = h4[i];
      any |= (v.x != 0.f) | (v.y != 0.f) | (v.z != 0.f) | (v.w != 0.f);
    }
    if (any) nz_sh = 1;
  }
  if (w == 0) {
    // weight pairs for lg h-part (cols 0..63)
    const f32x2* w0row = (const f32x2*)&Wpi[(size_t)lane * 78];
    #pragma unroll
    for (int k2 = 0; k2 < 32; ++k2) wpi0_p[k2] = w0row[k2];
    bpi0 = bpi[lane];
    if (lane < 26) {
      const f32x2* w1row = (const f32x2*)&Wpi[(size_t)(64 + lane) * 78];
      #pragma unroll
      for (int k2 = 0; k2 < 32; ++k2) wpi1_p[k2] = w1row[k2];
      bpi1 = bpi[64 + lane];
    }
    // Wf state columns: g-part (14..27) and b (28) kept in regs
    #pragma unroll
    for (int k = 0; k < 14; ++k) wfsg[k] = Wf[(size_t)lane * WFCOLS + CONVOUT + 14 + k];
    wfs28 = Wf[(size_t)lane * WFCOLS + CONVOUT + 28];
    bf_r = bf[lane];
    bhr_r = bhh[lane]; bhz_r = bhh[64 + lane]; bhn_r = bhh[128 + lane];
    wc0 = Wc[lane]; wc1 = Wc[64 + lane]; bc0 = bc[0];
    wl0 = Wl[lane]; wl1 = Wl[64 + lane]; wl2 = Wl[128 + lane];
    bl0 = bl[0]; bl1 = bl[1]; bl2 = bl[2];
    bb0d = (double)bb[0]; bb1d = (double)bb[1];
    if (lane < 14) { wbs0 = Wb[CONVOUT + lane]; wbs1 = Wb[(size_t)WBCOLS + CONVOUT + lane]; }
    const float* r0 = inp + (size_t)n * DIN + CONVOUT;
    #pragma unroll
    for (int k = 0; k < 5; ++k) {
      int ttv = (int)r0[k], cntv = (int)r0[5 + k] - 1, objv = (int)r0[10 + k];
      float v = 0.f;
      if (lane < 5)       v = (lane == ttv) ? 1.f : 0.f;
      else if (lane < 8)  v = ((lane - 5) == cntv) ? 1.f : 0.f;
      else if (lane < 14) v = ((lane - 8) == objv) ? 1.f : 0.f;
      mtr[k] = v;
      // precomputed one-hot column sums (per-lane scalars):
      const float* wfr = Wf + (size_t)lane * WFCOLS + CONVOUT;
      WfrM[k] = wfr[ttv] + wfr[5 + cntv] + wfr[8 + objv];
      const float* wp0 = Wpi + (size_t)lane * 78 + 64;
      WpiM0[k] = wp0[ttv] + wp0[5 + cntv] + wp0[8 + objv];
      if (lane < 26) {
        const float* wp1 = Wpi + (size_t)(64 + lane) * 78 + 64;
        WpiM1[k] = wp1[ttv] + wp1[5 + cntv] + wp1[8 + objv];
      }
    }
    // packed state layout: lanes 0-13 r, 14-27 g, 28 b, 29-33 p
    int src = -1;
    if (lane < 14)       { dsto = 5 + lane;          src = dsto; }
    else if (lane < 28)  { dsto = 83 + (lane - 14);  src = dsto; }
    else if (lane == 28) { dsto = 97;                src = 97; }
    else if (lane < 34)  { dsto = lane - 29;         src = dsto; }
    rgbp = (src >= 0) ? hx[(size_t)n * STATE + src] : 0.f;
    hreg = hx[(size_t)n * STATE + 19 + lane];
  }
  __syncthreads();   // nz_sh ready
  if (w == 0) {
    if (nz_sh == 0) {   // new episode (hx all zero): p[0]=1, r=g=M[:,0]
      const float* r0 = inp + (size_t)n * DIN + CONVOUT;
      int tt0 = (int)r0[0], cnt0 = (int)r0[5] - 1, obj0 = (int)r0[10];
      if (lane == 29) rgbp = 1.f;
      else if (lane < 14) rgbp = mtr[0];
      else if (lane >= 14 && lane < 28) {
        int j = lane - 14;
        rgbp = (j < 5) ? ((j == tt0) ? 1.f : 0.f)
             : (j < 8) ? (((j - 5) == cnt0) ? 1.f : 0.f)
                       : (((j - 8) == obj0) ? 1.f : 0.f);
      }
    }
    // S recurrence init: S = dot(g0, Wbs) fp64
    #pragma unroll
    for (int j = 0; j < 14; ++j) {
      double gv = (double)rlane(rgbp, 14 + j);
      S0 += gv * (double)rlane(wbs0, j);
      S1 += gv * (double)rlane(wbs1, j);
    }
    // running-sum inits from initial r0 / g0 / b0
    R_s = 0.f; accR0_run = 0.f; accR1_run = 0.f;
    #pragma unroll
    for (int j = 0; j < 14; ++j) {
      float rv = rlane(rgbp, j);
      R_s = fmaf(Wf[(size_t)lane * WFCOLS + CONVOUT + j], rv, R_s);
      accR0_run = fmaf(Wpi[(size_t)lane * 78 + 64 + j], rv, accR0_run);
      if (lane < 26) accR1_run = fmaf(Wpi[(size_t)(64 + lane) * 78 + 64 + j], rv, accR1_run);
    }
    G_s = 0.f;
    #pragma unroll
    for (int j = 0; j < 14; ++j) G_s = fmaf(wfsg[j], rlane(rgbp, 14 + j), G_s);
    float b0v = rlane(rgbp, 28);
    // t=0 data
    float xf0 = Xf[(size_t)n * 64 + lane];
    gum0 = Gg[(size_t)n * NG + lane];
    gum1 = (lane < 26) ? Gg[(size_t)n * NG + 64 + lane] : 0.0;
    xb0 = Xb[(size_t)n * 2 + 0]; xb1 = Xb[(size_t)n * 2 + 1];
    gb0 = Gb[(size_t)n * 2 + 0]; gb1 = Gb[(size_t)n * 2 + 1];
    // s(0) and publish [s, h]
    sv_own = xf0 + bf_r + R_s + G_s + b0v * wfs28;
    sh_lds[lane] = sv_own;
    sh_lds[64 + lane] = hreg;
    // xf prefetch one step deep (consumed at end of phase C for s(t+1))
    xfp = Xf[((size_t)((T_STEPS > 1) ? 1 : 0) * NB + n) * 64 + lane];
  }
  __syncthreads();

  const size_t outF = (size_t)T_STEPS * NB * STATE;

  #pragma unroll 1
  for (int t = 0; t < T_STEPS; ++t) {
    float cg = 0.f;
    double cgd = 0.0;

    if (w == 0) {
      // ---- slack work (runs concurrent with waves1-3 gi) ----
      float p0 = wl0 * hreg, p1 = wl1 * hreg, p2 = wl2 * hreg;
      float cga = fmaf(wc1, hreg, wc0 * sv_own);
      // DPP 4-way sum reduce -> lane 63
      #define DPP_SUM4(C, RM) \
        { p0 += dpp_mv<C,RM>(p0, 0.f); p1 += dpp_mv<C,RM>(p1, 0.f); \
          p2 += dpp_mv<C,RM>(p2, 0.f); cga += dpp_mv<C,RM>(cga, 0.f); }
      DPP_SUM4(0x111, 0xF) DPP_SUM4(0x112, 0xF) DPP_SUM4(0x114, 0xF)
      DPP_SUM4(0x118, 0xF) DPP_SUM4(0x142, 0xA) DPP_SUM4(0x143, 0xC)
      #undef DPP_SUM4
      float P0 = rlane(p0, 63) + bl0, P1 = rlane(p1, 63) + bl1, P2 = rlane(p2, 63) + bl2;
      float CGA = rlane(cga, 63);
      float mx = fmaxf(P0, fmaxf(P1, P2));
      float e0 = expf(P0 - mx), e1 = expf(P1 - mx), e2 = expf(P2 - mx);
      float se = e0 + e1 + e2;
      float l0 = e0 / se, l1 = e1 / se, l2 = e2 / se;
      cg = 1.f / (1.f + expf(-(CGA + bc0)));
      cgd = (double)cg;
      // pconv: p values are uniform via readlane
      float pv0 = rlane(rgbp, 29), pv1 = rlane(rgbp, 30), pv2 = rlane(rgbp, 31);
      float pv3 = rlane(rgbp, 32), pv4 = rlane(rgbp, 33);
      float pc0 = pv0 * l1 + pv1 * l2;
      float pc1 = pv0 * l0 + pv1 * l1 + pv2 * l2;
      float pc2 = pv1 * l0 + pv2 * l1 + pv3 * l2;
      float pc3 = pv2 * l0 + pv3 * l1 + pv4 * l2;
      float pc4 = pv3 * l0 + pv4 * l1;
      // p update (lanes 29-33), r update (lanes 0-13)
      if (lane >= 29 && lane < 34) {
        float pcl = (lane == 29) ? pc0 : (lane == 30) ? pc1 : (lane == 31) ? pc2
                  : (lane == 32) ? pc3 : pc4;
        rgbp = cg * pcl + (1.f - cg) * rgbp;
      }
      if (lane < 14) {
        float rn = pc0 * mtr[0] + pc1 * mtr[1] + pc2 * mtr[2] + pc3 * mtr[3] + pc4 * mtr[4];
        rgbp = cg * rn + (1.f - cg) * rgbp;
      }
      // running-sum updates (r-dependent parts)
      float rd0 = pc0 * WpiM0[0] + pc1 * WpiM0[1] + pc2 * WpiM0[2] + pc3 * WpiM0[3] + pc4 * WpiM0[4];
      accR0_run = cg * rd0 + (1.f - cg) * accR0_run;
      float rd1 = pc0 * WpiM1[0] + pc1 * WpiM1[1] + pc2 * WpiM1[2] + pc3 * WpiM1[3] + pc4 * WpiM1[4];
      accR1_run = cg * rd1 + (1.f - cg) * accR1_run;
      float rfd = pc0 * WfrM[0] + pc1 * WfrM[1] + pc2 * WfrM[2] + pc3 * WfrM[3] + pc4 * WfrM[4];
      R_s = cg * rfd + (1.f - cg) * R_s;
    } else {
      // ---- waves 1..3: gi = Wih . [s, h] + bih via uniform b64 broadcast ----
      const f32x2* shp = (const f32x2*)sh_lds;
      f32x2 acc0 = {bih_r, 0.f}, acc1 = {0.f, 0.f};
      #pragma unroll
      for (int k2 = 0; k2 < 64; k2 += 2) {
        f32x2 v0 = shp[k2], v1 = shp[k2 + 1];
        acc0.x = fmaf(wih_p[k2].x,     v0.x, acc0.x);
        acc0.y = fmaf(wih_p[k2].y,     v0.y, acc0.y);
        acc1.x = fmaf(wih_p[k2 + 1].x, v1.x, acc1.x);
        acc1.y = fmaf(wih_p[k2 + 1].y, v1.y, acc1.y);
      }
      gi_lds[tid - 64] = (acc0.x + acc0.y) + (acc1.x + acc1.y);
    }
    bar_lds();   // ---- bar_gi ----

    if (w == 0) {
      // prefetch t+1 inputs now; consumed next iteration
      int tn = (t + 1 < T_STEPS) ? t + 1 : t;
      int tpp = (t + 2 < T_STEPS) ? t + 2 : T_STEPS - 1;
      double gum0n = Gg[(size_t)tn * NB * NG + (size_t)n * NG + lane];
      double gum1n = (lane < 26) ? Gg[(size_t)tn * NB * NG + (size_t)n * NG + 64 + lane] : 0.0;
      double xb0n = Xb[((size_t)tn * NB + n) * 2 + 0];
      double xb1n = Xb[((size_t)tn * NB + n) * 2 + 1];
      double gb0n = Gb[((size_t)tn * NB + n) * 2 + 0];
      double gb1n = Gb[((size_t)tn * NB + n) * 2 + 1];

      // gates + h update
      float g0 = gi_lds[lane], g1 = gi_lds[64 + lane], g2 = gi_lds[128 + lane];
      float rg = 1.f / (1.f + expf(-(g0 + bhr_r)));
      float z  = 1.f / (1.f + expf(-(g1 + bhz_r)));
      float nn = tanhf(g2 + rg * bhn_r);
      float hnew = (1.f - z) * nn;
      hreg = cg * hnew + (1.f - cg) * hreg;
      sh_lds[64 + lane] = hreg;   // publish h (next gi + own pair-broadcast)

      // lg h-part via uniform b64 broadcast pairs (r-part is accR*_run)
      const f32x2* hp = (const f32x2*)&sh_lds[64];
      f32x2 A0 = {bpi0 + accR0_run, 0.f}, B0 = {0.f, 0.f};
      f32x2 A1 = {bpi1 + accR1_run, 0.f}, B1 = {0.f, 0.f};
      #pragma unroll
      for (int k2 = 0; k2 < 32; k2 += 2) {
        f32x2 h0 = hp[k2], h1 = hp[k2 + 1];
        A0.x = fmaf(wpi0_p[k2].x,     h0.x, A0.x);
        A0.y = fmaf(wpi0_p[k2].y,     h0.y, A0.y);
        B0.x = fmaf(wpi0_p[k2 + 1].x, h1.x, B0.x);
        B0.y = fmaf(wpi0_p[k2 + 1].y, h1.y, B0.y);
        A1.x = fmaf(wpi1_p[k2].x,     h0.x, A1.x);
        A1.y = fmaf(wpi1_p[k2].y,     h0.y, A1.y);
        B1.x = fmaf(wpi1_p[k2 + 1].x, h1.x, B1.x);
        B1.y = fmaf(wpi1_p[k2 + 1].y, h1.y, B1.y);
      }
      float a0 = (A0.x + A0.y) + (B0.x + B0.y);
      float a1 = (A1.x + A1.y) + (B1.x + B1.y);

      float vb0 = (float)(gum0 + (double)a0);
      float vb1 = (lane < 26) ? (float)(gum1 + (double)a1) : NEGINFF;
      // DPP (max, runner-up) reduce -> lane 63
      float m1 = fmaxf(vb0, vb1), m2 = fminf(vb0, vb1);
      #define DPP_AMAX(C, RM) \
        { float o1 = dpp_mv<C,RM>(m1, NEGINFF), o2 = dpp_mv<C,RM>(m2, NEGINFF); \
          m2 = fmaxf(m2, fmaxf(o2, fminf(m1, o1))); m1 = fmaxf(m1, o1); }
      DPP_AMAX(0x111, 0xF) DPP_AMAX(0x112, 0xF) DPP_AMAX(0x114, 0xF)
      DPP_AMAX(0x118, 0xF) DPP_AMAX(0x142, 0xA) DPP_AMAX(0x143, 0xC)
      #undef DPP_AMAX
      float M1 = rlane(m1, 63), M2 = rlane(m2, 63);
      unsigned long long bm0 = __ballot(vb0 == M1);
      unsigned long long bm1 = __ballot(vb1 == M1);
      int gidx = bm0 ? (__ffsll(bm0) - 1) : (64 + __ffsll(bm1) - 1);
      if (M1 - M2 < 3e-5f) {
        // rare fp64 slow path: exact recompute, weights from global
        double e0d = (double)bpi0;
        double e1d = (lane < 26) ? (double)bpi1 : -1.0e300;
        #pragma unroll 1
        for (int k = 0; k < 64; ++k) {
          double hv2 = (double)rlane(hreg, k);
          e0d = fma((double)Wpi[(size_t)lane * 78 + k], hv2, e0d);
          if (lane < 26) e1d = fma((double)Wpi[(size_t)(64 + lane) * 78 + k], hv2, e1d);
        }
        #pragma unroll 1
        for (int k = 0; k < 14; ++k) {
          double rv = (double)rlane(rgbp, k);
          e0d = fma((double)Wpi[(size_t)lane * 78 + 64 + k], rv, e0d);
          if (lane < 26) e1d = fma((double)Wpi[(size_t)(64 + lane) * 78 + 64 + k], rv, e1d);
        }
        double kk0 = e0d + gum0;
        double kk1 = (lane < 26) ? e1d + gum1 : -1.0e300;
        double d1; int di;
        if (kk1 > kk0) { d1 = kk1; di = lane + 64; } else { d1 = kk0; di = lane; }
        #pragma unroll
        for (int off = 32; off; off >>= 1) {
          double od = __shfl_xor(d1, off, 64);
          int    oi = __shfl_xor(di, off, 64);
          if (od > d1 || (od == d1 && oi < di)) { d1 = od; di = oi; }
        }
        gidx = di;
      }
      // g update from sampled embedding
      int t1 = gidx / 18, rem = gidx - t1 * 18;
      int b1 = rem / 6, c1 = rem - b1 * 6;
      if (lane >= 14 && lane < 28) {
        int j = lane - 14;
        float ge = (j < 5) ? ((j == t1) ? 1.f : 0.f)
                 : (j < 8) ? (((j - 5) == b1) ? 1.f : 0.f)
                           : (((j - 8) == c1) ? 1.f : 0.f);
        rgbp = cg * ge + (1.f - cg) * rgbp;
      }
      // G_s running sum: Wfg . g(t)
      float gt = (t1 == 0) ? wfsg[0] : (t1 == 1) ? wfsg[1] : (t1 == 2) ? wfsg[2]
               : (t1 == 3) ? wfsg[3] : wfsg[4];
      float gbv = (b1 == 0) ? wfsg[5] : (b1 == 1) ? wfsg[6] : wfsg[7];
      float gcv = (c1 == 0) ? wfsg[8] : (c1 == 1) ? wfsg[9] : (c1 == 2) ? wfsg[10]
               : (c1 == 3) ? wfsg[11] : (c1 == 4) ? wfsg[12] : wfsg[13];
      G_s = cg * (gt + gbv + gcv) + (1.f - cg) * G_s;
      // b sample via fp64 scalar recurrence S = dot(g, Wbs)
      double u0 = (double)rlane(wbs0, t1) + (double)rlane(wbs0, 5 + b1) + (double)rlane(wbs0, 8 + c1);
      double u1 = (double)rlane(wbs1, t1) + (double)rlane(wbs1, 5 + b1) + (double)rlane(wbs1, 8 + c1);
      S0 = cgd * u0 + (1.0 - cgd) * S0;
      S1 = cgd * u1 + (1.0 - cgd) * S1;
      double lb0 = xb0 + bb0d + S0;
      double lb1 = xb1 + bb1d + S1;
      int bi = ((lb1 + gb1) > (lb0 + gb0)) ? 1 : 0;
      if (lane == 28) rgbp = (float)bi;

      // s(t+1) from running sums; publish for next gi
      float Bv = bi ? wfs28 : 0.f;
      sv_own = xfp + bf_r + (R_s + G_s) + Bv;
      sh_lds[lane] = sv_own;
      xfp = Xf[((size_t)tpp * NB + n) * 64 + lane];

      // stores (fire-and-forget; barriers never drain vmcnt)
      size_t rn = (size_t)t * NB + n;
      float* ob = out + rn * STATE;
      if (dsto >= 0) ob[dsto] = rgbp;
      ob[19 + lane] = hreg;
      lgst[rn * NG + lane] = a0;
      if (lane < 26) lgst[rn * NG + 64 + lane] = a1;
      if (lane == 0) {
        lbst[rn * 2 + 0] = (float)lb0; lbst[rn * 2 + 1] = (float)lb1;
        gidxst[rn] = gidx; bidxst[rn] = bi;
      }
      if (t == T_STEPS - 1) {
        float* of = out + outF + (size_t)n * STATE;
        if (dsto >= 0) of[dsto] = rgbp;
        of[19 + lane] = hreg;
      }
      // rotate prefetched data
      gum0 = gum0n; gum1 = gum1n;
      xb0 = xb0n; xb1 = xb1n; gb0 = gb0n; gb1 = gb1n;
    }
    bar_lds();   // ---- bar_s: new s,h published for next-step gi ----
  }
}

// ---------------- K4: deferred log-prob (fp32, fully parallel) ----------------
__global__ __launch_bounds__(256) void k_lp(const float* __restrict__ lgst,
                                            const float* __restrict__ lbst,
                                            const int* __restrict__ gidxst,
                                            const int* __restrict__ bidxst,
                                            float* __restrict__ out) {
  int tid = threadIdx.x, lane = tid & 63, w = tid >> 6;
  size_t rn = (size_t)blockIdx.x * 4 + w;   // < 16384
  const float* lg = lgst + rn * NG;
  float v0 = lg[lane];
  float v1 = (lane < 26) ? lg[64 + lane] : -3.0e38f;
  float ml = fmaxf(v0, v1);
  #pragma unroll
  for (int off = 32; off; off >>= 1) ml = fmaxf(ml, __shfl_xor(ml, off, 64));
  float e = expf(v0 - ml) + ((lane < 26) ? expf(v1 - ml) : 0.f);
  #pragma unroll
  for (int off = 32; off; off >>= 1) e += __shfl_xor(e, off, 64);
  int gi = gidxst[rn];
  float lpg = (lg[gi] - ml) - logf(e);
  float lb0 = lbst[rn * 2 + 0], lb1 = lbst[rn * 2 + 1];
  int bi = bidxst[rn];
  float mx = fmaxf(lb0, lb1);
  float seb = expf(lb0 - mx) + expf(lb1 - mx);
  float lpb = ((bi ? lb1 : lb0) - mx) - logf(seb);
  if (lane == 0) {
    int t = (int)(rn / NB), n = (int)(rn % NB);
    float lp = lpg + lpb;
    out[rn * STATE + 98] = lp;
    if (t == T_STEPS - 1) out[(size_t)T_STEPS * NB * STATE + (size_t)n * STATE + 98] = lp;
  }
}

// ---------------- launcher ----------------
extern "C" void kernel_launch(void* const* d_in, const int* in_sizes, int n_in,
                              void* d_out, int out_size, void* d_ws, size_t ws_size,
                              hipStream_t stream) {
  const float* inp = (const float*)d_in[0];
  const float* hx  = (const float*)d_in[1];
  const float* Wf  = (const float*)d_in[2];
  const float* bf  = (const float*)d_in[3];
  const float* Wih = (const float*)d_in[4];
  const float* bih = (const float*)d_in[5];
  const float* bhh = (const float*)d_in[6];
  const float* Wc  = (const float*)d_in[7];
  const float* bc  = (const float*)d_in[8];
  const float* Wl  = (const float*)d_in[9];
  const float* bl  = (const float*)d_in[10];
  const float* Wpi = (const float*)d_in[11];
  const float* bpi = (const float*)d_in[12];
  const float* Wb  = (const float*)d_in[13];
  const float* bb  = (const float*)d_in[14];
  float* out = (float*)d_out;

  // ws layout (doubles first for alignment), total ~35.5 MB:
  double* Gg = (double*)d_ws;                       // 128*128*90
  double* Gb = Gg + (size_t)T_STEPS * NB * NG;      // 128*128*2
  double* Xb = Gb + (size_t)T_STEPS * NB * 2;       // 16384*2
  double* Pd = Xb + (size_t)NROWS * 2;              // 4*16384*2
  float*  Wt = (float*)(Pd + (size_t)4 * NROWS * 2);// 4096*68
  float*  Xf = Wt + (size_t)4096 * 68;              // 16384*64
  float*  Pf = Xf + (size_t)NROWS * 64;             // 4*16384*64 (16.8 MB)
  // aliased onto Pf (consumed by k_reduce before k_scan writes these):
  float*  lgst = Pf;                                // 16384*90
  float*  lbst = lgst + (size_t)NROWS * NG;         // 16384*2
  int*    gidxst = (int*)(lbst + (size_t)NROWS * 2);// 16384
  int*    bidxst = gidxst + NROWS;                  // 16384

  k_transpose<<<(66 * 4096) / 256, 256, 0, stream>>>(Wf, Wb, Wt);
  k_gemm<<<1024, 256, 0, stream>>>(inp, Wt, Pf, Pd);
  {
    size_t tot = (size_t)NROWS * 64 + (size_t)NROWS * 2;
    k_reduce<<<(int)((tot + 255) / 256), 256, 0, stream>>>(Pf, Pd, Xf, Xb);
  }
  k_noise<<<T_STEPS, 256, 0, stream>>>(Gg, Gb);
  k_scan<<<NB, 256, 0, stream>>>(inp, hx, Wf, bf, Wih, bih, bhh, Wc, bc, Wl, bl,
                                 Wpi, bpi, Wb, bb, Xf, Xb, Gg, Gb,
                                 lgst, lbst, gidxst, bidxst, out);
  k_lp<<<NROWS / 4, 256, 0, stream>>>(lgst, lbst, gidxst, bidxst, out);
}